// Round 1
// baseline (100.440 us; speedup 1.0000x reference)
//
#include <hip/hip_runtime.h>

// IF neuron: v += x[t]; out = (v >= TH) ? TH : 0; v -= out;  over T=4 steps.
// x: [T=4, B=32, H=512, W=1024] fp32.  Output same shape/dtype.
// Per-spatial-element recurrence -> one thread owns 4 consecutive spatial
// elements (float4), keeps v in registers, loops over T.
// Memory-bound: 256 MiB in + 256 MiB out -> ~85 us at 6.3 TB/s.

#define TH 1.0f

__global__ __launch_bounds__(256) void IFNeuron_90048284328050_kernel(
    const float4* __restrict__ x, float4* __restrict__ out, int nvec) {
    int i = blockIdx.x * blockDim.x + threadIdx.x;
    if (i >= nvec) return;

    float vx = 0.f, vy = 0.f, vz = 0.f, vw = 0.f;
#pragma unroll
    for (int t = 0; t < 4; ++t) {
        float4 xt = x[(size_t)t * nvec + i];
        vx += xt.x; vy += xt.y; vz += xt.z; vw += xt.w;
        float4 o;
        o.x = (vx >= TH) ? TH : 0.f;
        o.y = (vy >= TH) ? TH : 0.f;
        o.z = (vz >= TH) ? TH : 0.f;
        o.w = (vw >= TH) ? TH : 0.f;
        vx -= o.x; vy -= o.y; vz -= o.z; vw -= o.w;
        out[(size_t)t * nvec + i] = o;
    }
}

extern "C" void kernel_launch(void* const* d_in, const int* in_sizes, int n_in,
                              void* d_out, int out_size, void* d_ws, size_t ws_size,
                              hipStream_t stream) {
    const float4* x = (const float4*)d_in[0];
    float4* out = (float4*)d_out;

    const int T = 4;
    int total = in_sizes[0];            // 67,108,864 floats
    int nspatial = total / T;           // 16,777,216
    int nvec = nspatial / 4;            // 4,194,304 float4 per timestep

    int block = 256;
    int grid = (nvec + block - 1) / block;
    IFNeuron_90048284328050_kernel<<<grid, block, 0, stream>>>(x, out, nvec);
}